// Round 4
// baseline (126.253 us; speedup 1.0000x reference)
//
#include <hip/hip_runtime.h>

#define NG 20          // NUM_GAUSSIANS
#define NL 80          // NUM_LETTERS
#define HS 400         // HIDDEN_SIZE
#define ASCALE 0.05f   // ATTENTION_SCALE
#define BB 1024        // B
#define UU 1024        // U
#define LOG2E 1.4426950408889634f

// ROUND 4 = MEASUREMENT ROUND: kernel body is byte-identical to round 3.
// kernel_launch fires it 5x back-to-back (idempotent: each launch fully
// rewrites w_t / k_out / phi from unchanged inputs). t_kernel =
// (dur4 - dur3) / 4 resolves whether we're at a harness measurement floor
// (~73us of poison fills) or the kernel itself is ~30us.
__global__ __launch_bounds__(256) void window_fused_kernel(
    const int*   __restrict__ text,    // [B,U]
    const int*   __restrict__ tlen,    // [B]
    const float* __restrict__ y0,      // [B,H]
    const float* __restrict__ prevk,   // [B,N]
    const float* __restrict__ W,       // [3N,H]
    const float* __restrict__ bias,    // [3N]
    float* __restrict__ w_t,           // [B,NL]
    float* __restrict__ k_out,         // [B,NG]
    float* __restrict__ phi_out)       // [B,U]
{
    const int b   = blockIdx.x;
    const int tid = threadIdx.x;

    __shared__ float yrow[HS];
    __shared__ float LAs[NG], B2s[NG], Ks[NG];
    __shared__ float wloc[NL];

    // ---- phase 1: y0 row via float4 (400 floats = 100 float4) ----
    if (tid < HS / 4) {
        reinterpret_cast<float4*>(yrow)[tid] =
            reinterpret_cast<const float4*>(y0 + b * HS)[tid];
    }
    if (tid < NL) wloc[tid] = 0.f;
    __syncthreads();

    // ---- phase 2: 60 linear outputs, float4 dot products ----
    if (tid < 3 * NG * 4) {                 // 240 active threads
        const int j = tid >> 2;             // output index 0..59
        const int p = tid & 3;              // 4-way K split (chunks of 100)
        const float4* wr = reinterpret_cast<const float4*>(W + j * HS + p * 100);
        const float4* yr = reinterpret_cast<const float4*>(yrow + p * 100);
        float s = 0.f;
        #pragma unroll 5
        for (int i = 0; i < 25; ++i) {
            const float4 w4 = wr[i];
            const float4 y4 = yr[i];
            s += w4.x * y4.x + w4.y * y4.y + w4.z * y4.z + w4.w * y4.w;
        }
        s += __shfl_down(s, 1, 4);
        s += __shfl_down(s, 2, 4);
        if (p == 0) {
            const float val = s + bias[j];
            if (j < NG) {
                LAs[j] = val * LOG2E;                       // log2(a)
            } else if (j < 2 * NG) {
                B2s[j - NG] = __expf(val) * LOG2E;          // b * log2e
            } else {
                const int g = j - 2 * NG;
                const float kk = __expf(val) * ASCALE + prevk[b * NG + g];
                Ks[g] = kk;
                k_out[b * NG + g] = kk;
            }
        }
    }
    __syncthreads();

    // hoist Gaussian params to registers (uniform LDS broadcast, read once)
    float la[NG], b2[NG], kg[NG];
    #pragma unroll
    for (int n = 0; n < NG; ++n) { la[n] = LAs[n]; b2[n] = B2s[n]; kg[n] = Ks[n]; }

    // ---- phase 3: phi + scatter ----
    const int len = tlen[b];
    #pragma unroll
    for (int ui = 0; ui < UU / 256; ++ui) {
        const int u = ui * 256 + tid;
        const int letter = text[b * UU + u];   // prefetch (coalesced, always)
        float s = 0.f;
        if (u < len) {
            const float uf = (float)u;
            #pragma unroll
            for (int n = 0; n < NG; ++n) {
                const float d = kg[n] - uf;
                s += exp2f(__builtin_fmaf(-b2[n] * d, d, la[n]));
            }
        }
        phi_out[b * UU + u] = s;
        if (s != 0.f) {
            atomicAdd(&wloc[letter], s);
        }
    }
    __syncthreads();

    // ---- phase 4 ----
    if (tid < NL) w_t[b * NL + tid] = wloc[tid];
}

extern "C" void kernel_launch(void* const* d_in, const int* in_sizes, int n_in,
                              void* d_out, int out_size, void* d_ws, size_t ws_size,
                              hipStream_t stream) {
    const int*   text  = (const int*)  d_in[0];
    const int*   tlen  = (const int*)  d_in[1];
    const float* y0    = (const float*)d_in[2];
    const float* prevk = (const float*)d_in[3];
    const float* W     = (const float*)d_in[4];
    const float* bias  = (const float*)d_in[5];

    float* out   = (float*)d_out;
    float* w_t   = out;                          // [B, NL]
    float* k_out = out + BB * NL;                // [B, NG]
    float* phi   = out + BB * NL + BB * NG;      // [B, U]

    // 5 identical launches (idempotent). Timing round: isolates kernel time
    // from the harness floor via dur slope.
    #pragma unroll
    for (int rep = 0; rep < 5; ++rep) {
        hipLaunchKernelGGL(window_fused_kernel, dim3(BB), dim3(256), 0, stream,
                           text, tlen, y0, prevk, W, bias, w_t, k_out, phi);
    }
}

// Round 5
// 75.694 us; speedup vs baseline: 1.6679x; 1.6679x over previous
//
#include <hip/hip_runtime.h>

#define NG 20          // NUM_GAUSSIANS
#define NL 80          // NUM_LETTERS
#define HS 400         // HIDDEN_SIZE
#define ASCALE 0.05f   // ATTENTION_SCALE
#define BB 1024        // B
#define UU 1024        // U
#define LOG2E 1.4426950408889634f

// One block per batch row, 256 threads (4 waves), single launch.
// Measured r4: kernel ~12.4us, harness floor ~64us. This round:
//  - __builtin_amdgcn_exp2f (raw v_exp_f32) instead of libm exp2f
//  - phase 3: 4 consecutive u per thread -> int4 text load (prefetched at
//    kernel entry), float4 phi store, 4 independent FMA/exp chains (ILP)
//  - __launch_bounds__(256,4): >=4 waves/EU so VGPR<=128, 4 blocks/CU
__global__ __launch_bounds__(256, 4) void window_fused_kernel(
    const int*   __restrict__ text,    // [B,U]
    const int*   __restrict__ tlen,    // [B]
    const float* __restrict__ y0,      // [B,H]
    const float* __restrict__ prevk,   // [B,N]
    const float* __restrict__ W,       // [3N,H]
    const float* __restrict__ bias,    // [3N]
    float* __restrict__ w_t,           // [B,NL]
    float* __restrict__ k_out,         // [B,NG]
    float* __restrict__ phi_out)       // [B,U]
{
    const int b   = blockIdx.x;
    const int tid = threadIdx.x;

    // ---- prefetch this thread's 4 letters NOW; consumed 2 phases later ----
    const int4 letters = reinterpret_cast<const int4*>(text + b * UU)[tid];
    const int  len     = tlen[b];

    __shared__ float yrow[HS];
    __shared__ float LAs[NG], B2s[NG], Ks[NG];
    __shared__ float wloc[NL];

    // ---- phase 1: y0 row via float4 (400 floats = 100 float4) ----
    if (tid < HS / 4) {
        reinterpret_cast<float4*>(yrow)[tid] =
            reinterpret_cast<const float4*>(y0 + b * HS)[tid];
    }
    if (tid < NL) wloc[tid] = 0.f;
    __syncthreads();

    // ---- phase 2: 60 linear outputs, float4 dot products ----
    if (tid < 3 * NG * 4) {                 // 240 active threads
        const int j = tid >> 2;             // output index 0..59
        const int p = tid & 3;              // 4-way K split (chunks of 100)
        const float4* wr = reinterpret_cast<const float4*>(W + j * HS + p * 100);
        const float4* yr = reinterpret_cast<const float4*>(yrow + p * 100);
        float s = 0.f;
        #pragma unroll 5
        for (int i = 0; i < 25; ++i) {
            const float4 w4 = wr[i];
            const float4 y4 = yr[i];
            s += w4.x * y4.x + w4.y * y4.y + w4.z * y4.z + w4.w * y4.w;
        }
        s += __shfl_down(s, 1, 4);
        s += __shfl_down(s, 2, 4);
        if (p == 0) {
            const float val = s + bias[j];
            if (j < NG) {
                LAs[j] = val * LOG2E;                       // log2(a)
            } else if (j < 2 * NG) {
                B2s[j - NG] = __expf(val) * LOG2E;          // b * log2e
            } else {
                const int g = j - 2 * NG;
                const float kk = __expf(val) * ASCALE + prevk[b * NG + g];
                Ks[g] = kk;
                k_out[b * NG + g] = kk;
            }
        }
    }
    __syncthreads();

    // hoist Gaussian params to registers (uniform LDS broadcast, read once)
    float la[NG], b2[NG], kg[NG];
    #pragma unroll
    for (int n = 0; n < NG; ++n) { la[n] = LAs[n]; b2[n] = B2s[n]; kg[n] = Ks[n]; }

    // ---- phase 3: 4 consecutive u per thread ----
    const int u0 = tid * 4;
    float s0 = 0.f, s1 = 0.f, s2 = 0.f, s3 = 0.f;
    if (u0 < len) {
        const float uf = (float)u0;
        #pragma unroll
        for (int n = 0; n < NG; ++n) {
            const float d0 = kg[n] - uf;
            const float d1 = d0 - 1.f;
            const float d2 = d0 - 2.f;
            const float d3 = d0 - 3.f;
            s0 += __builtin_amdgcn_exp2f(__builtin_fmaf(-b2[n] * d0, d0, la[n]));
            s1 += __builtin_amdgcn_exp2f(__builtin_fmaf(-b2[n] * d1, d1, la[n]));
            s2 += __builtin_amdgcn_exp2f(__builtin_fmaf(-b2[n] * d2, d2, la[n]));
            s3 += __builtin_amdgcn_exp2f(__builtin_fmaf(-b2[n] * d3, d3, la[n]));
        }
        // boundary mask (u0 itself is < len)
        if (u0 + 1 >= len) s1 = 0.f;
        if (u0 + 2 >= len) s2 = 0.f;
        if (u0 + 3 >= len) s3 = 0.f;
    }
    float4 phi4; phi4.x = s0; phi4.y = s1; phi4.z = s2; phi4.w = s3;
    reinterpret_cast<float4*>(phi_out + b * UU)[tid] = phi4;

    if (s0 != 0.f) atomicAdd(&wloc[letters.x], s0);
    if (s1 != 0.f) atomicAdd(&wloc[letters.y], s1);
    if (s2 != 0.f) atomicAdd(&wloc[letters.z], s2);
    if (s3 != 0.f) atomicAdd(&wloc[letters.w], s3);
    __syncthreads();

    // ---- phase 4 ----
    if (tid < NL) w_t[b * NL + tid] = wloc[tid];
}

extern "C" void kernel_launch(void* const* d_in, const int* in_sizes, int n_in,
                              void* d_out, int out_size, void* d_ws, size_t ws_size,
                              hipStream_t stream) {
    const int*   text  = (const int*)  d_in[0];
    const int*   tlen  = (const int*)  d_in[1];
    const float* y0    = (const float*)d_in[2];
    const float* prevk = (const float*)d_in[3];
    const float* W     = (const float*)d_in[4];
    const float* bias  = (const float*)d_in[5];

    float* out   = (float*)d_out;
    float* w_t   = out;                          // [B, NL]
    float* k_out = out + BB * NL;                // [B, NG]
    float* phi   = out + BB * NL + BB * NG;      // [B, U]

    hipLaunchKernelGGL(window_fused_kernel, dim3(BB), dim3(256), 0, stream,
                       text, tlen, y0, prevk, W, bias, w_t, k_out, phi);
}